// Round 6
// baseline (422.091 us; speedup 1.0000x reference)
//
#include <hip/hip_runtime.h>
#include <hip/hip_bf16.h>
#include <stdint.h>

// Problem constants
constexpr int BATCH = 64;
constexpr int NTOK  = 197;
constexpr int CDIM  = 768;
constexpr int NH    = 12;
constexpr int HD    = 64;
constexpr int MROWS = BATCH * NTOK;        // 12608
constexpr int MPAD  = 12672;               // 99 * 128
constexpr int LEFT  = 137;                 // int(0.7 * 196)
constexpr int KPAD  = 224;                 // keys padded (7 * 32)
constexpr int BH    = BATCH * NH;          // 768
constexpr int SPAD  = 208;                 // score row stride

// Output layout (flat float32, concatenated in return order)
constexpr size_t OUT_OFF_OUT   = 0;                                   // [64,197,768]
constexpr size_t OUT_OFF_INDEX = (size_t)BATCH * NTOK * CDIM;         // [64,137,768]
constexpr size_t OUT_OFF_IDX   = OUT_OFF_INDEX + (size_t)BATCH * LEFT * CDIM; // [64,137]
constexpr size_t OUT_OFF_CLS   = OUT_OFF_IDX + (size_t)BATCH * LEFT;  // [64,196]

// Workspace layout (float units; bf16 regions counted as elems/2)
constexpr size_t WS_CLSPH = 0;                                        // B*H*196
constexpr size_t WS_CLSF  = WS_CLSPH + (size_t)BH * (NTOK - 1);
constexpr size_t WS_IDXI  = WS_CLSF  + (size_t)BATCH * (NTOK - 1);
constexpr size_t WS_Q0    = WS_IDXI  + (size_t)BATCH * LEFT;          // [64,768]
constexpr size_t WS_XB    = WS_Q0  + (size_t)BATCH * CDIM;            // [MPAD,768] bf16
constexpr size_t WS_WB    = WS_XB  + (size_t)MPAD * CDIM / 2;         // [2304,768] bf16
constexpr size_t WS_PB    = WS_WB  + (size_t)3 * CDIM * CDIM / 2;     // [768,768] bf16
constexpr size_t WS_QB    = WS_PB  + (size_t)CDIM * CDIM / 2;         // [BH,197,64] bf16
constexpr size_t WS_KB    = WS_QB  + (size_t)BH * NTOK * HD / 2;      // [BH,197,64] bf16
constexpr size_t WS_VTB   = WS_KB  + (size_t)BH * NTOK * HD / 2;      // [BH,64,224] bf16
constexpr size_t WS_AOB   = WS_VTB + (size_t)BH * HD * KPAD / 2;      // [MPAD,768] bf16
constexpr size_t WS_U     = WS_AOB + (size_t)MPAD * CDIM / 2;         // [BH,768] fp32
constexpr size_t WS_S     = WS_U   + (size_t)BH * CDIM;               // [BH,208] fp32

typedef __attribute__((ext_vector_type(8))) short short8;
typedef __attribute__((ext_vector_type(4))) float floatx4;

__device__ __forceinline__ ushort f2bf(float x) {
    __hip_bfloat16 h = __float2bfloat16(x);
    return *(ushort*)&h;
}

// async global->LDS, 16B per lane; LDS dest must be wave-uniform base + lane*16
__device__ __forceinline__ void load_lds16(const ushort* g, ushort* l) {
    __builtin_amdgcn_global_load_lds(
        (const __attribute__((address_space(1))) uint32_t*)(uintptr_t)g,
        (__attribute__((address_space(3))) uint32_t*)(uint32_t)(uintptr_t)l,
        16, 0, 0);
}

// ---------------------------------------------------------------------------
// fp32 -> bf16 cast, zero padding up to npad4 float4s.
// ---------------------------------------------------------------------------
__global__ __launch_bounds__(256) void cast_kernel(const float* __restrict__ src,
                                                   ushort* __restrict__ dst,
                                                   int n4, int npad4) {
    int i = blockIdx.x * 256 + threadIdx.x;
    if (i >= npad4) return;
    ushort4 h4 = make_ushort4(0, 0, 0, 0);
    if (i < n4) {
        float4 a = ((const float4*)src)[i];
        h4 = make_ushort4(f2bf(a.x), f2bf(a.y), f2bf(a.z), f2bf(a.w));
    }
    ((ushort4*)dst)[i] = h4;
}

// zero the padded key columns of Vt (cols 197..223) — poison would NaN the PV MFMA
__global__ void vt_pad_kernel(ushort* __restrict__ Vtb) {
    int tid = blockIdx.x * 256 + threadIdx.x;
    constexpr int PADW = KPAD - NTOK;               // 27
    if (tid >= BH * HD * PADW) return;
    int row = tid / PADW;
    int col = NTOK + (tid - row * PADW);
    Vtb[(size_t)row * KPAD + col] = 0;
}

// ---------------------------------------------------------------------------
// Exact fp32 q row-0 projection: q0[b, c] = x[b,0,:] . qkv_w[c,:] + qkv_b[c]
// ---------------------------------------------------------------------------
__global__ __launch_bounds__(256) void q0_kernel(const float* __restrict__ x,
                                                 const float* __restrict__ qkv_w,
                                                 const float* __restrict__ qkv_b,
                                                 float* __restrict__ q0) {
    int tid = blockIdx.x * 256 + threadIdx.x;
    if (tid >= BATCH * CDIM) return;
    int b = tid / CDIM, c = tid - b * CDIM;
    const float* xr = x + (size_t)b * NTOK * CDIM;
    const float* wr = qkv_w + (size_t)c * CDIM;
    float s = 0.f;
    for (int k = 0; k < CDIM; k += 4) {
        float4 xv = *(const float4*)(xr + k);
        float4 wv = *(const float4*)(wr + k);
        s += xv.x * wv.x + xv.y * wv.y + xv.z * wv.z + xv.w * wv.w;
    }
    q0[tid] = s + qkv_b[c];
}

// ---------------------------------------------------------------------------
// u[bh, c] = sum_d q0[b, h*64+d] * Wk[h*64+d, c]   (Wk = qkv_w rows 768..1535)
// ---------------------------------------------------------------------------
__global__ __launch_bounds__(256) void u_kernel(const float* __restrict__ q0,
                                                const float* __restrict__ qkv_w,
                                                float* __restrict__ U) {
    const int bh = blockIdx.x;
    const int b  = bh / NH;
    const int h  = bh - b * NH;
    const int t  = threadIdx.x;

    __shared__ float q0s[HD];
    if (t < HD) q0s[t] = q0[(size_t)b * CDIM + h * HD + t];
    __syncthreads();

    const float* wk = qkv_w + (size_t)(CDIM + h * HD) * CDIM;
    float a0 = 0.f, a1 = 0.f, a2 = 0.f;
    for (int d = 0; d < HD; d++) {
        const float qd = q0s[d];
        const float* row = wk + (size_t)d * CDIM;
        a0 = fmaf(qd, row[t],       a0);
        a1 = fmaf(qd, row[t + 256], a1);
        a2 = fmaf(qd, row[t + 512], a2);
    }
    float* ub = U + (size_t)bh * CDIM;
    ub[t] = a0; ub[t + 256] = a1; ub[t + 512] = a2;
}

// ---------------------------------------------------------------------------
// S[bh, j] = u[bh,:] . x[b,j,:]   — one wave per (j, b).
// ---------------------------------------------------------------------------
__global__ __launch_bounds__(64) void score_kernel(const float* __restrict__ x,
                                                   const float* __restrict__ U,
                                                   float* __restrict__ S) {
    const int j    = blockIdx.x;
    const int b    = blockIdx.y;
    const int lane = threadIdx.x;

    const float* xr = x + ((size_t)b * NTOK + j) * CDIM;
    float4 xv[3];
#pragma unroll
    for (int i = 0; i < 3; i++) xv[i] = *(const float4*)(xr + lane * 4 + i * 256);

    for (int h = 0; h < NH; h++) {
        const float* ur = U + (size_t)(b * NH + h) * CDIM;
        float s = 0.f;
#pragma unroll
        for (int i = 0; i < 3; i++) {
            float4 uv = *(const float4*)(ur + lane * 4 + i * 256);
            s += xv[i].x * uv.x + xv[i].y * uv.y + xv[i].z * uv.z + xv[i].w * uv.w;
        }
#pragma unroll
        for (int off = 32; off >= 1; off >>= 1) s += __shfl_xor(s, off);
        if (lane == 0) S[(size_t)(b * NH + h) * SPAD + j] = s;
    }
}

// ---------------------------------------------------------------------------
// Softmax of cls row per bh: s_j = (S[j] + q0_h.bk_h) * scale; probs for j>=1.
// ---------------------------------------------------------------------------
__global__ __launch_bounds__(64) void cls_softmax_kernel(const float* __restrict__ S,
                                                         const float* __restrict__ q0,
                                                         const float* __restrict__ qkv_b,
                                                         float* __restrict__ CLSPH) {
    const int bh   = blockIdx.x;
    const int b    = bh / NH;
    const int h    = bh - b * NH;
    const int lane = threadIdx.x;

    float qb = q0[(size_t)b * CDIM + h * HD + lane] * qkv_b[CDIM + h * HD + lane];
#pragma unroll
    for (int off = 32; off >= 1; off >>= 1) qb += __shfl_xor(qb, off);

    const float* Sr = S + (size_t)bh * SPAD;
    float sv[4];
    float mloc = -INFINITY;
#pragma unroll
    for (int i = 0; i < 4; i++) {
        const int j = lane + i * 64;
        sv[i] = (j < NTOK) ? (Sr[j] + qb) * 0.125f : -INFINITY;
        mloc = fmaxf(mloc, sv[i]);
    }
#pragma unroll
    for (int off = 32; off >= 1; off >>= 1) mloc = fmaxf(mloc, __shfl_xor(mloc, off));

    float pv[4], ls = 0.f;
#pragma unroll
    for (int i = 0; i < 4; i++) { pv[i] = expf(sv[i] - mloc); ls += pv[i]; }  // exp(-inf)=0
#pragma unroll
    for (int off = 32; off >= 1; off >>= 1) ls += __shfl_xor(ls, off);

    const float inv = 1.f / ls;
#pragma unroll
    for (int i = 0; i < 4; i++) {
        const int j = lane + i * 64;
        if (j >= 1 && j < NTOK)
            CLSPH[(size_t)bh * (NTOK - 1) + (j - 1)] = pv[i] * inv;
    }
}

// ---------------------------------------------------------------------------
// Plain-bf16 MFMA GEMM: O = A @ W^T + bias.  128x128 tile, BK=32, 4 waves.
// LDS k-chunk XOR swizzle (s(row) = (row ^ row>>2) & 3) breaks the 8-way
// bank conflict of the naive [row][kq] layout; staging fetches chunk
// (t&3)^s(row) so readers at slot fq^s(fr) see global chunk fq.
// MODE 0: fp32 row-major O0[Mvalid, N].
// MODE 1: qkv scatter (bf16): q -> O0q[bh][tok][64], k -> O1k[bh][tok][64],
//         v -> O2vt[bh][d][KPAD]  (transposed!)
// ---------------------------------------------------------------------------
template <int MODE>
__global__ __launch_bounds__(256) void mfma_gemm(const ushort* __restrict__ A,
                                                 const ushort* __restrict__ W,
                                                 const float* __restrict__ bias,
                                                 float* __restrict__ O0f,
                                                 ushort* __restrict__ O0q,
                                                 ushort* __restrict__ O1k,
                                                 ushort* __restrict__ O2vt,
                                                 int Mvalid, int N, int K) {
    __shared__ ushort sA[128 * 32], sB[128 * 32];

    const int t    = threadIdx.x;
    const int lane = t & 63;
    const int w    = t >> 6;
    const int wm   = (w & 1) * 64;
    const int wn   = (w >> 1) * 64;
    const int rowBase = blockIdx.y * 128;
    const int colBase = blockIdx.x * 128;

    floatx4 acc[4][4];
#pragma unroll
    for (int i = 0; i < 4; i++)
#pragma unroll
        for (int j = 0; j < 4; j++)
#pragma unroll
            for (int r = 0; r < 4; r++) acc[i][j][r] = 0.f;

    // staging with XOR-swizzled source k-chunk
    const int srow = t >> 2;
    const int ssw  = (srow ^ (srow >> 2)) & 3;
    const int skp  = ((t & 3) ^ ssw) * 8;
    const ushort* gA0 = A + (size_t)(rowBase + srow) * K + skp;
    const ushort* gB0 = W + (size_t)(colBase + srow) * K + skp;
    const size_t rstep = (size_t)64 * K;    // row+64: s unchanged (bit6/bit4 not in s)
    const int fr  = lane & 15;
    const int fq  = lane >> 4;
    const int swz = (fq ^ fr ^ (fr >> 2)) & 3;   // slot holding global chunk fq

    for (int k0 = 0; k0 < K; k0 += 32) {
        __syncthreads();
        load_lds16(gA0 + k0,         sA + t * 8);
        load_lds16(gA0 + k0 + rstep, sA + t * 8 + 2048);
        load_lds16(gB0 + k0,         sB + t * 8);
        load_lds16(gB0 + k0 + rstep, sB + t * 8 + 2048);
        __syncthreads();

        short8 af[4], bf[4];
#pragma unroll
        for (int i = 0; i < 4; i++) {
            af[i] = *(const short8*)&sA[(wm + i * 16 + fr) * 32 + swz * 8];
            bf[i] = *(const short8*)&sB[(wn + i * 16 + fr) * 32 + swz * 8];
        }
#pragma unroll
        for (int i = 0; i < 4; i++)
#pragma unroll
            for (int j = 0; j < 4; j++)
                acc[i][j] = __builtin_amdgcn_mfma_f32_16x16x32_bf16(af[i], bf[j], acc[i][j], 0, 0, 0);
    }

    // epilogue: C/D layout col(n)=lane&15, row(m)=(lane>>4)*4+reg
    int mv[4][4], bv_[4][4], tokv[4][4];
#pragma unroll
    for (int i = 0; i < 4; i++)
#pragma unroll
        for (int r = 0; r < 4; r++) {
            const int m = rowBase + wm + i * 16 + fq * 4 + r;
            mv[i][r] = m;
            if (MODE == 1) {
                const int b = m / NTOK;
                bv_[i][r] = b;
                tokv[i][r] = m - b * NTOK;
            }
        }

#pragma unroll
    for (int j = 0; j < 4; j++) {
        const int n  = colBase + wn + j * 16 + fr;
        const float bq = bias[n];
        if (MODE == 0) {
#pragma unroll
            for (int i = 0; i < 4; i++)
#pragma unroll
                for (int r = 0; r < 4; r++) {
                    const int m = mv[i][r];
                    if (m < Mvalid) O0f[(size_t)m * N + n] = acc[i][j][r] + bq;
                }
        } else {
            const int which = n / CDIM;
            const int nc    = n - which * CDIM;
            const int h     = nc >> 6;
            const int d     = nc & 63;
#pragma unroll
            for (int i = 0; i < 4; i++)
#pragma unroll
                for (int r = 0; r < 4; r++) {
                    const int m = mv[i][r];
                    if (m < Mvalid) {
                        const int bh = bv_[i][r] * NH + h;
                        const int tok = tokv[i][r];
                        const ushort val = f2bf(acc[i][j][r] + bq);
                        if (which == 0)      O0q[((size_t)bh * NTOK + tok) * HD + d] = val;
                        else if (which == 1) O1k[((size_t)bh * NTOK + tok) * HD + d] = val;
                        else                 O2vt[((size_t)bh * HD + d) * KPAD + tok] = val;
                    }
                }
        }
    }
}

// ---------------------------------------------------------------------------
// MFMA flash attention: one wave (64 threads) per (q-tile, b*h).
// S^T = K.Q^T so queries sit in C-columns; online softmax per-lane + two
// shfl_xor quad-reduces. P via 1KB LDS roundtrip; PV uses transposed-V frags.
// ---------------------------------------------------------------------------
__global__ __launch_bounds__(64) void attn_mfma_kernel(const ushort* __restrict__ Qb,
                                                       const ushort* __restrict__ Kb,
                                                       const ushort* __restrict__ Vtb,
                                                       ushort* __restrict__ AOb) {
    const int qt = blockIdx.x;          // 0..12
    const int bh = blockIdx.y;          // 0..767
    const int b  = bh / NH;
    const int h  = bh - b * NH;
    const int lane = threadIdx.x;
    const int qc   = lane & 15;
    const int quad = lane >> 4;

    __shared__ ushort Pl[16][32];
    __shared__ float  alf[16], lf[16];

    const ushort* Qh = Qb  + (size_t)bh * NTOK * HD;
    const ushort* Kh = Kb  + (size_t)bh * NTOK * HD;
    const ushort* Vh = Vtb + (size_t)bh * HD * KPAD;

    const int qrow = min(qt * 16 + qc, NTOK - 1);
    const short8 qf0 = *(const short8*)(Qh + (size_t)qrow * HD + quad * 8);
    const short8 qf1 = *(const short8*)(Qh + (size_t)qrow * HD + 32 + quad * 8);

    floatx4 o[4];
#pragma unroll
    for (int s = 0; s < 4; s++)
#pragma unroll
        for (int r = 0; r < 4; r++) o[s][r] = 0.f;
    float m = -INFINITY, l = 0.f;

    for (int c0 = 0; c0 < NTOK; c0 += 32) {
        const int kr0 = min(c0 + qc, NTOK - 1);
        const int kr1 = min(c0 + 16 + qc, NTOK - 1);
        short8 kf00 = *(const short8*)(Kh + (size_t)kr0 * HD + quad * 8);
        short8 kf01 = *(const short8*)(Kh + (size_t)kr0 * HD + 32 + quad * 8);
        short8 kf10 = *(const short8*)(Kh + (size_t)kr1 * HD + quad * 8);
        short8 kf11 = *(const short8*)(Kh + (size_t)kr1 * HD + 32 + quad * 8);

        floatx4 s0 = {0.f, 0.f, 0.f, 0.f}, s1 = {0.f, 0.f, 0.f, 0.f};
        s0 = __builtin_amdgcn_mfma_f32_16x16x32_bf16(kf00, qf0, s0, 0, 0, 0);
        s0 = __builtin_amdgcn_mfma_f32_16x16x32_bf16(kf01, qf1, s0, 0, 0, 0);
        s1 = __builtin_amdgcn_mfma_f32_16x16x32_bf16(kf10, qf0, s1, 0, 0, 0);
        s1 = __builtin_amdgcn_mfma_f32_16x16x32_bf16(kf11, qf1, s1, 0, 0, 0);

        float sv[8];
        float mloc = -INFINITY;
#pragma unroll
        for (int r = 0; r < 4; r++) {
            const int key0 = c0 + quad * 4 + r;
            const int key1 = key0 + 16;
            sv[r]     = (key0 < NTOK) ? s0[r] * 0.125f : -1e30f;
            sv[4 + r] = (key1 < NTOK) ? s1[r] * 0.125f : -1e30f;
            mloc = fmaxf(mloc, fmaxf(sv[r], sv[4 + r]));
        }
        mloc = fmaxf(mloc, __shfl_xor(mloc, 16));
        mloc = fmaxf(mloc, __shfl_xor(mloc, 32));
        const float mnew  = fmaxf(m, mloc);
        const float alpha = __expf(m - mnew);
        float p[8], ps = 0.f;
#pragma unroll
        for (int i = 0; i < 8; i++) { p[i] = __expf(sv[i] - mnew); ps += p[i]; }
        ps += __shfl_xor(ps, 16);
        ps += __shfl_xor(ps, 32);
        l = l * alpha + ps;
        m = mnew;

#pragma unroll
        for (int r = 0; r < 4; r++) {
            Pl[qc][quad * 4 + r]      = f2bf(p[r]);
            Pl[qc][16 + quad * 4 + r] = f2bf(p[4 + r]);
        }
        if (quad == 0) alf[qc] = alpha;
        __syncthreads();

        float ar[4];
#pragma unroll
        for (int r = 0; r < 4; r++) ar[r] = alf[quad * 4 + r];
#pragma unroll
        for (int s = 0; s < 4; s++)
#pragma unroll
            for (int r = 0; r < 4; r++) o[s][r] *= ar[r];

        const short8 pf = *(const short8*)&Pl[qc][quad * 8];
#pragma unroll
        for (int s = 0; s < 4; s++) {
            const short8 vf = *(const short8*)(Vh + (size_t)(s * 16 + qc) * KPAD + c0 + quad * 8);
            o[s] = __builtin_amdgcn_mfma_f32_16x16x32_bf16(pf, vf, o[s], 0, 0, 0);
        }
        __syncthreads();
    }

    if (quad == 0) lf[qc] = l;
    __syncthreads();

#pragma unroll
    for (int r = 0; r < 4; r++) {
        const int tok = qt * 16 + quad * 4 + r;
        if (tok >= NTOK) continue;
        const float inv = 1.f / lf[quad * 4 + r];
        ushort* dst = AOb + ((size_t)(b * NTOK + tok)) * CDIM + h * HD;
#pragma unroll
        for (int s = 0; s < 4; s++) dst[s * 16 + qc] = f2bf(o[s][r] * inv);
    }
}

// ---------------------------------------------------------------------------
__global__ void cls_mean_kernel(const float* __restrict__ CLSPH,
                                float* __restrict__ clsF,
                                float* __restrict__ outCls) {
    int tid = blockIdx.x * 256 + threadIdx.x;
    if (tid >= BATCH * (NTOK - 1)) return;
    int b = tid / (NTOK - 1);
    int j = tid - b * (NTOK - 1);
    float s = 0.f;
#pragma unroll
    for (int h = 0; h < NH; h++) s += CLSPH[(size_t)(b * NH + h) * (NTOK - 1) + j];
    float v = s * (1.f / 12.f);
    clsF[tid]   = v;
    outCls[tid] = v;
}

__global__ void topk_kernel(const float* __restrict__ clsF,
                            int* __restrict__ idxI,
                            float* __restrict__ idxOut) {
    const int b = blockIdx.x;
    const int t = threadIdx.x;
    __shared__ float v[NTOK - 1];
    if (t < NTOK - 1) v[t] = clsF[b * (NTOK - 1) + t];
    __syncthreads();
    if (t < NTOK - 1) {
        float vi = v[t];
        int rank = 0;
        for (int j = 0; j < NTOK - 1; j++) {
            float vj = v[j];
            rank += (vj > vi) || (vj == vi && j < t);
        }
        if (rank < LEFT) {
            idxI[b * LEFT + rank]   = t;
            idxOut[b * LEFT + rank] = (float)t;
        }
    }
}

// index = broadcast idx over channel dim, float4-vectorized (CDIM%4==0)
__global__ void fill_index_kernel(const int* __restrict__ idxI,
                                  float* __restrict__ dst) {
    int tid = blockIdx.x * 256 + threadIdx.x;
    constexpr int C4 = CDIM / 4;
    if (tid >= BATCH * LEFT * C4) return;
    float v = (float)idxI[tid / C4];
    ((float4*)dst)[tid] = make_float4(v, v, v, v);
}

extern "C" void kernel_launch(void* const* d_in, const int* in_sizes, int n_in,
                              void* d_out, int out_size, void* d_ws, size_t ws_size,
                              hipStream_t stream) {
    const float* x      = (const float*)d_in[0];
    const float* qkv_w  = (const float*)d_in[1];  // [2304,768]
    const float* qkv_b  = (const float*)d_in[2];  // [2304]
    const float* proj_w = (const float*)d_in[3];  // [768,768]
    const float* proj_b = (const float*)d_in[4];  // [768]
    float* out = (float*)d_out;

    float*  ws    = (float*)d_ws;
    float*  clsph = ws + WS_CLSPH;
    float*  clsf  = ws + WS_CLSF;
    int*    idxi  = (int*)(ws + WS_IDXI);
    float*  q0    = ws + WS_Q0;
    ushort* xb    = (ushort*)(ws + WS_XB);
    ushort* wb    = (ushort*)(ws + WS_WB);
    ushort* pb    = (ushort*)(ws + WS_PB);
    ushort* qb    = (ushort*)(ws + WS_QB);
    ushort* kb    = (ushort*)(ws + WS_KB);
    ushort* vtb   = (ushort*)(ws + WS_VTB);
    ushort* aob   = (ushort*)(ws + WS_AOB);
    float*  U     = ws + WS_U;
    float*  S     = ws + WS_S;

    // 1) fp32 -> bf16 casts (+row padding for MPAD), Vt pad-column zeroing
    {
        int n4 = MROWS * CDIM / 4, np4 = MPAD * CDIM / 4;
        cast_kernel<<<(np4 + 255) / 256, 256, 0, stream>>>(x, xb, n4, np4);
        int w4 = 3 * CDIM * CDIM / 4;
        cast_kernel<<<(w4 + 255) / 256, 256, 0, stream>>>(qkv_w, wb, w4, w4);
        int p4 = CDIM * CDIM / 4;
        cast_kernel<<<(p4 + 255) / 256, 256, 0, stream>>>(proj_w, pb, p4, p4);
        int vp = BH * HD * (KPAD - NTOK);
        vt_pad_kernel<<<(vp + 255) / 256, 256, 0, stream>>>(vtb);
    }

    // 2) Exact fp32 cls-score side path (top-k precision domain)
    q0_kernel<<<(BATCH * CDIM + 255) / 256, 256, 0, stream>>>(x, qkv_w, qkv_b, q0);
    u_kernel<<<BH, 256, 0, stream>>>(q0, qkv_w, U);
    score_kernel<<<dim3(NTOK, BATCH), 64, 0, stream>>>(x, U, S);
    cls_softmax_kernel<<<BH, 64, 0, stream>>>(S, q0, qkv_b, clsph);

    // 3) QKV projection (bf16 MFMA) + scatter q/k bf16, v transposed bf16
    mfma_gemm<1><<<dim3(3 * CDIM / 128, MPAD / 128), 256, 0, stream>>>(
        xb, wb, qkv_b, nullptr, qb, kb, vtb, MROWS, 3 * CDIM, CDIM);

    // 4) MFMA flash attention -> bf16 pre-proj out
    attn_mfma_kernel<<<dim3(13, BH), 64, 0, stream>>>(qb, kb, vtb, aob);

    // 5) Output projection (bf16 MFMA) -> fp32 out
    mfma_gemm<0><<<dim3(CDIM / 128, MPAD / 128), 256, 0, stream>>>(
        aob, pb, proj_b, out + OUT_OFF_OUT, nullptr, nullptr, nullptr,
        MROWS, CDIM, CDIM);

    // 6) Head-average cls attention (exact path)
    cls_mean_kernel<<<(BATCH * (NTOK - 1) + 255) / 256, 256, 0, stream>>>(
        clsph, clsf, out + OUT_OFF_CLS);

    // 7) Exact top-137 (stable descending)
    topk_kernel<<<BATCH, 256, 0, stream>>>(clsf, idxi, out + OUT_OFF_IDX);

    // 8) Broadcast indices over channels (float4)
    fill_index_kernel<<<((size_t)BATCH * LEFT * (CDIM / 4) + 255) / 256, 256, 0, stream>>>(
        idxi, out + OUT_OFF_INDEX);
}

// Round 7
// 392.116 us; speedup vs baseline: 1.0764x; 1.0764x over previous
//
#include <hip/hip_runtime.h>
#include <hip/hip_bf16.h>
#include <stdint.h>

// Problem constants
constexpr int BATCH = 64;
constexpr int NTOK  = 197;
constexpr int CDIM  = 768;
constexpr int NH    = 12;
constexpr int HD    = 64;
constexpr int MROWS = BATCH * NTOK;        // 12608
constexpr int MPAD  = 12672;               // 99 * 128
constexpr int LEFT  = 137;                 // int(0.7 * 196)
constexpr int KPAD  = 224;                 // keys padded (7 * 32)
constexpr int BH    = BATCH * NH;          // 768
constexpr int SPAD  = 208;                 // score row stride

// Output layout (flat float32, concatenated in return order)
constexpr size_t OUT_OFF_OUT   = 0;                                   // [64,197,768]
constexpr size_t OUT_OFF_INDEX = (size_t)BATCH * NTOK * CDIM;         // [64,137,768]
constexpr size_t OUT_OFF_IDX   = OUT_OFF_INDEX + (size_t)BATCH * LEFT * CDIM; // [64,137]
constexpr size_t OUT_OFF_CLS   = OUT_OFF_IDX + (size_t)BATCH * LEFT;  // [64,196]

// Workspace layout (float units; bf16 regions counted as elems/2)
constexpr size_t WS_CLSPH = 0;                                        // B*H*196
constexpr size_t WS_CLSF  = WS_CLSPH + (size_t)BH * (NTOK - 1);
constexpr size_t WS_IDXI  = WS_CLSF  + (size_t)BATCH * (NTOK - 1);
constexpr size_t WS_Q0    = WS_IDXI  + (size_t)BATCH * LEFT;          // [64,768]
constexpr size_t WS_XB    = WS_Q0  + (size_t)BATCH * CDIM;            // [MPAD,768] bf16
constexpr size_t WS_WB    = WS_XB  + (size_t)MPAD * CDIM / 2;         // [2304,768] bf16
constexpr size_t WS_PB    = WS_WB  + (size_t)3 * CDIM * CDIM / 2;     // [768,768] bf16
constexpr size_t WS_QB    = WS_PB  + (size_t)CDIM * CDIM / 2;         // [BH,197,64] bf16
constexpr size_t WS_KB    = WS_QB  + (size_t)BH * NTOK * HD / 2;      // [BH,197,64] bf16
constexpr size_t WS_VTB   = WS_KB  + (size_t)BH * NTOK * HD / 2;      // [BH,64,224] bf16
constexpr size_t WS_AOB   = WS_VTB + (size_t)BH * HD * KPAD / 2;      // [MPAD,768] bf16
constexpr size_t WS_U     = WS_AOB + (size_t)MPAD * CDIM / 2;         // [BH,768] fp32
constexpr size_t WS_S     = WS_U   + (size_t)BH * CDIM;               // [BH,208] fp32

typedef __attribute__((ext_vector_type(8))) short short8;
typedef __attribute__((ext_vector_type(4))) float floatx4;

__device__ __forceinline__ ushort f2bf(float x) {
    __hip_bfloat16 h = __float2bfloat16(x);
    return *(ushort*)&h;
}

// async global->LDS, 16B per lane; LDS dest must be wave-uniform base + lane*16
__device__ __forceinline__ void load_lds16(const ushort* g, ushort* l) {
    __builtin_amdgcn_global_load_lds(
        (const __attribute__((address_space(1))) uint32_t*)(uintptr_t)g,
        (__attribute__((address_space(3))) uint32_t*)(uint32_t)(uintptr_t)l,
        16, 0, 0);
}

// ---------------------------------------------------------------------------
// fp32 -> bf16 cast, zero padding up to npad4 float4s.
// ---------------------------------------------------------------------------
__global__ __launch_bounds__(256) void cast_kernel(const float* __restrict__ src,
                                                   ushort* __restrict__ dst,
                                                   int n4, int npad4) {
    int i = blockIdx.x * 256 + threadIdx.x;
    if (i >= npad4) return;
    ushort4 h4 = make_ushort4(0, 0, 0, 0);
    if (i < n4) {
        float4 a = ((const float4*)src)[i];
        h4 = make_ushort4(f2bf(a.x), f2bf(a.y), f2bf(a.z), f2bf(a.w));
    }
    ((ushort4*)dst)[i] = h4;
}

// zero the padded key columns of Vt (cols 197..223) — poison would NaN the PV MFMA
__global__ void vt_pad_kernel(ushort* __restrict__ Vtb) {
    int tid = blockIdx.x * 256 + threadIdx.x;
    constexpr int PADW = KPAD - NTOK;               // 27
    if (tid >= BH * HD * PADW) return;
    int row = tid / PADW;
    int col = NTOK + (tid - row * PADW);
    Vtb[(size_t)row * KPAD + col] = 0;
}

// ---------------------------------------------------------------------------
// Exact fp32 q row-0 projection: q0[b, c] = x[b,0,:] . qkv_w[c,:] + qkv_b[c]
// ---------------------------------------------------------------------------
__global__ __launch_bounds__(256) void q0_kernel(const float* __restrict__ x,
                                                 const float* __restrict__ qkv_w,
                                                 const float* __restrict__ qkv_b,
                                                 float* __restrict__ q0) {
    int tid = blockIdx.x * 256 + threadIdx.x;
    if (tid >= BATCH * CDIM) return;
    int b = tid / CDIM, c = tid - b * CDIM;
    const float* xr = x + (size_t)b * NTOK * CDIM;
    const float* wr = qkv_w + (size_t)c * CDIM;
    float s = 0.f;
    for (int k = 0; k < CDIM; k += 4) {
        float4 xv = *(const float4*)(xr + k);
        float4 wv = *(const float4*)(wr + k);
        s += xv.x * wv.x + xv.y * wv.y + xv.z * wv.z + xv.w * wv.w;
    }
    q0[tid] = s + qkv_b[c];
}

// ---------------------------------------------------------------------------
// u[bh, c] = sum_d q0[b, h*64+d] * Wk[h*64+d, c]   (Wk = qkv_w rows 768..1535)
// ---------------------------------------------------------------------------
__global__ __launch_bounds__(256) void u_kernel(const float* __restrict__ q0,
                                                const float* __restrict__ qkv_w,
                                                float* __restrict__ U) {
    const int bh = blockIdx.x;
    const int b  = bh / NH;
    const int h  = bh - b * NH;
    const int t  = threadIdx.x;

    __shared__ float q0s[HD];
    if (t < HD) q0s[t] = q0[(size_t)b * CDIM + h * HD + t];
    __syncthreads();

    const float* wk = qkv_w + (size_t)(CDIM + h * HD) * CDIM;
    float a0 = 0.f, a1 = 0.f, a2 = 0.f;
    for (int d = 0; d < HD; d++) {
        const float qd = q0s[d];
        const float* row = wk + (size_t)d * CDIM;
        a0 = fmaf(qd, row[t],       a0);
        a1 = fmaf(qd, row[t + 256], a1);
        a2 = fmaf(qd, row[t + 512], a2);
    }
    float* ub = U + (size_t)bh * CDIM;
    ub[t] = a0; ub[t + 256] = a1; ub[t + 512] = a2;
}

// ---------------------------------------------------------------------------
// S[bh, j] = u[bh,:] . x[b,j,:]   — one wave per (j, b).
// ---------------------------------------------------------------------------
__global__ __launch_bounds__(64) void score_kernel(const float* __restrict__ x,
                                                   const float* __restrict__ U,
                                                   float* __restrict__ S) {
    const int j    = blockIdx.x;
    const int b    = blockIdx.y;
    const int lane = threadIdx.x;

    const float* xr = x + ((size_t)b * NTOK + j) * CDIM;
    float4 xv[3];
#pragma unroll
    for (int i = 0; i < 3; i++) xv[i] = *(const float4*)(xr + lane * 4 + i * 256);

    for (int h = 0; h < NH; h++) {
        const float* ur = U + (size_t)(b * NH + h) * CDIM;
        float s = 0.f;
#pragma unroll
        for (int i = 0; i < 3; i++) {
            float4 uv = *(const float4*)(ur + lane * 4 + i * 256);
            s += xv[i].x * uv.x + xv[i].y * uv.y + xv[i].z * uv.z + xv[i].w * uv.w;
        }
#pragma unroll
        for (int off = 32; off >= 1; off >>= 1) s += __shfl_xor(s, off);
        if (lane == 0) S[(size_t)(b * NH + h) * SPAD + j] = s;
    }
}

// ---------------------------------------------------------------------------
// Softmax of cls row per bh: s_j = (S[j] + q0_h.bk_h) * scale; probs for j>=1.
// ---------------------------------------------------------------------------
__global__ __launch_bounds__(64) void cls_softmax_kernel(const float* __restrict__ S,
                                                         const float* __restrict__ q0,
                                                         const float* __restrict__ qkv_b,
                                                         float* __restrict__ CLSPH) {
    const int bh   = blockIdx.x;
    const int b    = bh / NH;
    const int h    = bh - b * NH;
    const int lane = threadIdx.x;

    float qb = q0[(size_t)b * CDIM + h * HD + lane] * qkv_b[CDIM + h * HD + lane];
#pragma unroll
    for (int off = 32; off >= 1; off >>= 1) qb += __shfl_xor(qb, off);

    const float* Sr = S + (size_t)bh * SPAD;
    float sv[4];
    float mloc = -INFINITY;
#pragma unroll
    for (int i = 0; i < 4; i++) {
        const int j = lane + i * 64;
        sv[i] = (j < NTOK) ? (Sr[j] + qb) * 0.125f : -INFINITY;
        mloc = fmaxf(mloc, sv[i]);
    }
#pragma unroll
    for (int off = 32; off >= 1; off >>= 1) mloc = fmaxf(mloc, __shfl_xor(mloc, off));

    float pv[4], ls = 0.f;
#pragma unroll
    for (int i = 0; i < 4; i++) { pv[i] = expf(sv[i] - mloc); ls += pv[i]; }  // exp(-inf)=0
#pragma unroll
    for (int off = 32; off >= 1; off >>= 1) ls += __shfl_xor(ls, off);

    const float inv = 1.f / ls;
#pragma unroll
    for (int i = 0; i < 4; i++) {
        const int j = lane + i * 64;
        if (j >= 1 && j < NTOK)
            CLSPH[(size_t)bh * (NTOK - 1) + (j - 1)] = pv[i] * inv;
    }
}

// ---------------------------------------------------------------------------
// Plain-bf16 MFMA GEMM: O = A @ W^T + bias.  128x128 tile, BK=32, 4 waves,
// 2-stage double-buffered LDS: prefetch tile k+1 right after the barrier so
// the global->LDS latency overlaps the tile-k MFMA compute (the per-iter
// vmcnt(0) drain before s_barrier then has nothing left to wait for).
// MODE 0: fp32 row-major O0[Mvalid, N].
// MODE 1: qkv scatter (bf16): q -> O0q[bh][tok][64], k -> O1k[bh][tok][64],
//         v -> O2vt[bh][d][KPAD]  (transposed!)
// ---------------------------------------------------------------------------
template <int MODE>
__global__ __launch_bounds__(256) void mfma_gemm(const ushort* __restrict__ A,
                                                 const ushort* __restrict__ W,
                                                 const float* __restrict__ bias,
                                                 float* __restrict__ O0f,
                                                 ushort* __restrict__ O0q,
                                                 ushort* __restrict__ O1k,
                                                 ushort* __restrict__ O2vt,
                                                 int Mvalid, int N, int K) {
    __shared__ ushort sA[2][128 * 32], sB[2][128 * 32];

    const int t    = threadIdx.x;
    const int lane = t & 63;
    const int w    = t >> 6;
    const int wm   = (w & 1) * 64;
    const int wn   = (w >> 1) * 64;
    const int rowBase = blockIdx.y * 128;
    const int colBase = blockIdx.x * 128;

    floatx4 acc[4][4];
#pragma unroll
    for (int i = 0; i < 4; i++)
#pragma unroll
        for (int j = 0; j < 4; j++)
#pragma unroll
            for (int r = 0; r < 4; r++) acc[i][j][r] = 0.f;

    const int srow = t >> 2;
    const int skp  = (t & 3) * 8;
    const ushort* gA0 = A + (size_t)(rowBase + srow) * K + skp;
    const ushort* gB0 = W + (size_t)(colBase + srow) * K + skp;
    const size_t rstep = (size_t)64 * K;
    const int fr = lane & 15;
    const int fq = lane >> 4;

    // prologue: stage k0=0 into buffer 0
    load_lds16(gA0,         sA[0] + t * 8);
    load_lds16(gA0 + rstep, sA[0] + t * 8 + 2048);
    load_lds16(gB0,         sB[0] + t * 8);
    load_lds16(gB0 + rstep, sB[0] + t * 8 + 2048);

    int cur = 0;
    for (int k0 = 0; k0 < K; k0 += 32) {
        __syncthreads();   // drains vmcnt -> buf[cur] ready; orders buf[cur^1] reuse
        const int kn = k0 + 32;
        if (kn < K) {      // prefetch next tile into the other buffer
            load_lds16(gA0 + kn,         sA[cur ^ 1] + t * 8);
            load_lds16(gA0 + kn + rstep, sA[cur ^ 1] + t * 8 + 2048);
            load_lds16(gB0 + kn,         sB[cur ^ 1] + t * 8);
            load_lds16(gB0 + kn + rstep, sB[cur ^ 1] + t * 8 + 2048);
        }

        short8 af[4], bf[4];
#pragma unroll
        for (int i = 0; i < 4; i++) {
            af[i] = *(const short8*)&sA[cur][(wm + i * 16 + fr) * 32 + fq * 8];
            bf[i] = *(const short8*)&sB[cur][(wn + i * 16 + fr) * 32 + fq * 8];
        }
#pragma unroll
        for (int i = 0; i < 4; i++)
#pragma unroll
            for (int j = 0; j < 4; j++)
                acc[i][j] = __builtin_amdgcn_mfma_f32_16x16x32_bf16(af[i], bf[j], acc[i][j], 0, 0, 0);
        cur ^= 1;
    }

    // epilogue: C/D layout col(n)=lane&15, row(m)=(lane>>4)*4+reg
#pragma unroll
    for (int j = 0; j < 4; j++) {
        const int n  = colBase + wn + j * 16 + fr;
        const float bq = bias[n];
        if (MODE == 0) {
#pragma unroll
            for (int i = 0; i < 4; i++) {
                const int mb = rowBase + wm + i * 16 + fq * 4;
#pragma unroll
                for (int r = 0; r < 4; r++) {
                    const int m = mb + r;
                    if (m < Mvalid) O0f[(size_t)m * N + n] = acc[i][j][r] + bq;
                }
            }
        } else {
            const int which = n / CDIM;
            const int nc    = n - which * CDIM;
            const int h     = nc >> 6;
            const int d     = nc & 63;
#pragma unroll
            for (int i = 0; i < 4; i++) {
                const int mb = rowBase + wm + i * 16 + fq * 4;
#pragma unroll
                for (int r = 0; r < 4; r++) {
                    const int m = mb + r;
                    if (m < Mvalid) {
                        const int b   = m / NTOK;
                        const int tok = m - b * NTOK;
                        const int bh  = b * NH + h;
                        const ushort val = f2bf(acc[i][j][r] + bq);
                        if (which == 0)      O0q[((size_t)bh * NTOK + tok) * HD + d] = val;
                        else if (which == 1) O1k[((size_t)bh * NTOK + tok) * HD + d] = val;
                        else                 O2vt[((size_t)bh * HD + d) * KPAD + tok] = val;
                    }
                }
            }
        }
    }
}

// ---------------------------------------------------------------------------
// MFMA flash attention: one wave (64 threads) per (q-tile, b*h).
// S^T = K.Q^T so queries sit in C-columns; online softmax per-lane + two
// shfl_xor quad-reduces. P via 1KB LDS roundtrip; PV uses transposed-V frags.
// ---------------------------------------------------------------------------
__global__ __launch_bounds__(64) void attn_mfma_kernel(const ushort* __restrict__ Qb,
                                                       const ushort* __restrict__ Kb,
                                                       const ushort* __restrict__ Vtb,
                                                       ushort* __restrict__ AOb) {
    const int qt = blockIdx.x;          // 0..12
    const int bh = blockIdx.y;          // 0..767
    const int b  = bh / NH;
    const int h  = bh - b * NH;
    const int lane = threadIdx.x;
    const int qc   = lane & 15;
    const int quad = lane >> 4;

    __shared__ ushort Pl[16][32];
    __shared__ float  alf[16], lf[16];

    const ushort* Qh = Qb  + (size_t)bh * NTOK * HD;
    const ushort* Kh = Kb  + (size_t)bh * NTOK * HD;
    const ushort* Vh = Vtb + (size_t)bh * HD * KPAD;

    const int qrow = min(qt * 16 + qc, NTOK - 1);
    const short8 qf0 = *(const short8*)(Qh + (size_t)qrow * HD + quad * 8);
    const short8 qf1 = *(const short8*)(Qh + (size_t)qrow * HD + 32 + quad * 8);

    floatx4 o[4];
#pragma unroll
    for (int s = 0; s < 4; s++)
#pragma unroll
        for (int r = 0; r < 4; r++) o[s][r] = 0.f;
    float m = -INFINITY, l = 0.f;

    for (int c0 = 0; c0 < NTOK; c0 += 32) {
        const int kr0 = min(c0 + qc, NTOK - 1);
        const int kr1 = min(c0 + 16 + qc, NTOK - 1);
        short8 kf00 = *(const short8*)(Kh + (size_t)kr0 * HD + quad * 8);
        short8 kf01 = *(const short8*)(Kh + (size_t)kr0 * HD + 32 + quad * 8);
        short8 kf10 = *(const short8*)(Kh + (size_t)kr1 * HD + quad * 8);
        short8 kf11 = *(const short8*)(Kh + (size_t)kr1 * HD + 32 + quad * 8);

        floatx4 s0 = {0.f, 0.f, 0.f, 0.f}, s1 = {0.f, 0.f, 0.f, 0.f};
        s0 = __builtin_amdgcn_mfma_f32_16x16x32_bf16(kf00, qf0, s0, 0, 0, 0);
        s0 = __builtin_amdgcn_mfma_f32_16x16x32_bf16(kf01, qf1, s0, 0, 0, 0);
        s1 = __builtin_amdgcn_mfma_f32_16x16x32_bf16(kf10, qf0, s1, 0, 0, 0);
        s1 = __builtin_amdgcn_mfma_f32_16x16x32_bf16(kf11, qf1, s1, 0, 0, 0);

        float sv[8];
        float mloc = -INFINITY;
#pragma unroll
        for (int r = 0; r < 4; r++) {
            const int key0 = c0 + quad * 4 + r;
            const int key1 = key0 + 16;
            sv[r]     = (key0 < NTOK) ? s0[r] * 0.125f : -1e30f;
            sv[4 + r] = (key1 < NTOK) ? s1[r] * 0.125f : -1e30f;
            mloc = fmaxf(mloc, fmaxf(sv[r], sv[4 + r]));
        }
        mloc = fmaxf(mloc, __shfl_xor(mloc, 16));
        mloc = fmaxf(mloc, __shfl_xor(mloc, 32));
        const float mnew  = fmaxf(m, mloc);
        const float alpha = __expf(m - mnew);
        float p[8], ps = 0.f;
#pragma unroll
        for (int i = 0; i < 8; i++) { p[i] = __expf(sv[i] - mnew); ps += p[i]; }
        ps += __shfl_xor(ps, 16);
        ps += __shfl_xor(ps, 32);
        l = l * alpha + ps;
        m = mnew;

#pragma unroll
        for (int r = 0; r < 4; r++) {
            Pl[qc][quad * 4 + r]      = f2bf(p[r]);
            Pl[qc][16 + quad * 4 + r] = f2bf(p[4 + r]);
        }
        if (quad == 0) alf[qc] = alpha;
        __syncthreads();

        float ar[4];
#pragma unroll
        for (int r = 0; r < 4; r++) ar[r] = alf[quad * 4 + r];
#pragma unroll
        for (int s = 0; s < 4; s++)
#pragma unroll
            for (int r = 0; r < 4; r++) o[s][r] *= ar[r];

        const short8 pf = *(const short8*)&Pl[qc][quad * 8];
#pragma unroll
        for (int s = 0; s < 4; s++) {
            const short8 vf = *(const short8*)(Vh + (size_t)(s * 16 + qc) * KPAD + c0 + quad * 8);
            o[s] = __builtin_amdgcn_mfma_f32_16x16x32_bf16(pf, vf, o[s], 0, 0, 0);
        }
        __syncthreads();
    }

    if (quad == 0) lf[qc] = l;
    __syncthreads();

#pragma unroll
    for (int r = 0; r < 4; r++) {
        const int tok = qt * 16 + quad * 4 + r;
        if (tok >= NTOK) continue;
        const float inv = 1.f / lf[quad * 4 + r];
        ushort* dst = AOb + ((size_t)(b * NTOK + tok)) * CDIM + h * HD;
#pragma unroll
        for (int s = 0; s < 4; s++) dst[s * 16 + qc] = f2bf(o[s][r] * inv);
    }
}

// ---------------------------------------------------------------------------
__global__ void cls_mean_kernel(const float* __restrict__ CLSPH,
                                float* __restrict__ clsF,
                                float* __restrict__ outCls) {
    int tid = blockIdx.x * 256 + threadIdx.x;
    if (tid >= BATCH * (NTOK - 1)) return;
    int b = tid / (NTOK - 1);
    int j = tid - b * (NTOK - 1);
    float s = 0.f;
#pragma unroll
    for (int h = 0; h < NH; h++) s += CLSPH[(size_t)(b * NH + h) * (NTOK - 1) + j];
    float v = s * (1.f / 12.f);
    clsF[tid]   = v;
    outCls[tid] = v;
}

__global__ void topk_kernel(const float* __restrict__ clsF,
                            int* __restrict__ idxI,
                            float* __restrict__ idxOut) {
    const int b = blockIdx.x;
    const int t = threadIdx.x;
    __shared__ float v[NTOK - 1];
    if (t < NTOK - 1) v[t] = clsF[b * (NTOK - 1) + t];
    __syncthreads();
    if (t < NTOK - 1) {
        float vi = v[t];
        int rank = 0;
        for (int j = 0; j < NTOK - 1; j++) {
            float vj = v[j];
            rank += (vj > vi) || (vj == vi && j < t);
        }
        if (rank < LEFT) {
            idxI[b * LEFT + rank]   = t;
            idxOut[b * LEFT + rank] = (float)t;
        }
    }
}

// index = broadcast idx over channel dim, float4-vectorized (CDIM%4==0)
__global__ void fill_index_kernel(const int* __restrict__ idxI,
                                  float* __restrict__ dst) {
    int tid = blockIdx.x * 256 + threadIdx.x;
    constexpr int C4 = CDIM / 4;
    if (tid >= BATCH * LEFT * C4) return;
    float v = (float)idxI[tid / C4];
    ((float4*)dst)[tid] = make_float4(v, v, v, v);
}

extern "C" void kernel_launch(void* const* d_in, const int* in_sizes, int n_in,
                              void* d_out, int out_size, void* d_ws, size_t ws_size,
                              hipStream_t stream) {
    const float* x      = (const float*)d_in[0];
    const float* qkv_w  = (const float*)d_in[1];  // [2304,768]
    const float* qkv_b  = (const float*)d_in[2];  // [2304]
    const float* proj_w = (const float*)d_in[3];  // [768,768]
    const float* proj_b = (const float*)d_in[4];  // [768]
    float* out = (float*)d_out;

    float*  ws    = (float*)d_ws;
    float*  clsph = ws + WS_CLSPH;
    float*  clsf  = ws + WS_CLSF;
    int*    idxi  = (int*)(ws + WS_IDXI);
    float*  q0    = ws + WS_Q0;
    ushort* xb    = (ushort*)(ws + WS_XB);
    ushort* wb    = (ushort*)(ws + WS_WB);
    ushort* pb    = (ushort*)(ws + WS_PB);
    ushort* qb    = (ushort*)(ws + WS_QB);
    ushort* kb    = (ushort*)(ws + WS_KB);
    ushort* vtb   = (ushort*)(ws + WS_VTB);
    ushort* aob   = (ushort*)(ws + WS_AOB);
    float*  U     = ws + WS_U;
    float*  S     = ws + WS_S;

    // 1) fp32 -> bf16 casts (+row padding for MPAD), Vt pad-column zeroing
    {
        int n4 = MROWS * CDIM / 4, np4 = MPAD * CDIM / 4;
        cast_kernel<<<(np4 + 255) / 256, 256, 0, stream>>>(x, xb, n4, np4);
        int w4 = 3 * CDIM * CDIM / 4;
        cast_kernel<<<(w4 + 255) / 256, 256, 0, stream>>>(qkv_w, wb, w4, w4);
        int p4 = CDIM * CDIM / 4;
        cast_kernel<<<(p4 + 255) / 256, 256, 0, stream>>>(proj_w, pb, p4, p4);
        int vp = BH * HD * (KPAD - NTOK);
        vt_pad_kernel<<<(vp + 255) / 256, 256, 0, stream>>>(vtb);
    }

    // 2) Exact fp32 cls-score side path (top-k precision domain)
    q0_kernel<<<(BATCH * CDIM + 255) / 256, 256, 0, stream>>>(x, qkv_w, qkv_b, q0);
    u_kernel<<<BH, 256, 0, stream>>>(q0, qkv_w, U);
    score_kernel<<<dim3(NTOK, BATCH), 64, 0, stream>>>(x, U, S);
    cls_softmax_kernel<<<BH, 64, 0, stream>>>(S, q0, qkv_b, clsph);

    // 3) QKV projection (bf16 MFMA) + scatter q/k bf16, v transposed bf16
    mfma_gemm<1><<<dim3(3 * CDIM / 128, MPAD / 128), 256, 0, stream>>>(
        xb, wb, qkv_b, nullptr, qb, kb, vtb, MROWS, 3 * CDIM, CDIM);

    // 4) MFMA flash attention -> bf16 pre-proj out
    attn_mfma_kernel<<<dim3(13, BH), 64, 0, stream>>>(qb, kb, vtb, aob);

    // 5) Output projection (bf16 MFMA) -> fp32 out
    mfma_gemm<0><<<dim3(CDIM / 128, MPAD / 128), 256, 0, stream>>>(
        aob, pb, proj_b, out + OUT_OFF_OUT, nullptr, nullptr, nullptr,
        MROWS, CDIM, CDIM);

    // 6) Head-average cls attention (exact path)
    cls_mean_kernel<<<(BATCH * (NTOK - 1) + 255) / 256, 256, 0, stream>>>(
        clsph, clsf, out + OUT_OFF_CLS);

    // 7) Exact top-137 (stable descending)
    topk_kernel<<<BATCH, 256, 0, stream>>>(clsf, idxi, out + OUT_OFF_IDX);

    // 8) Broadcast indices over channels (float4)
    fill_index_kernel<<<((size_t)BATCH * LEFT * (CDIM / 4) + 255) / 256, 256, 0, stream>>>(
        idxi, out + OUT_OFF_INDEX);
}

// Round 8
// 382.578 us; speedup vs baseline: 1.1033x; 1.0249x over previous
//
#include <hip/hip_runtime.h>
#include <hip/hip_bf16.h>
#include <stdint.h>

// Problem constants
constexpr int BATCH = 64;
constexpr int NTOK  = 197;
constexpr int CDIM  = 768;
constexpr int NH    = 12;
constexpr int HD    = 64;
constexpr int MROWS = BATCH * NTOK;        // 12608
constexpr int MPAD  = 12672;               // 99 * 128
constexpr int LEFT  = 137;                 // int(0.7 * 196)
constexpr int KPAD  = 224;                 // keys padded (7 * 32)
constexpr int BH    = BATCH * NH;          // 768
constexpr int SPAD  = 208;                 // score row stride
constexpr int NROWB = MPAD / 128;          // 99 row-blocks

// Output layout (flat float32, concatenated in return order)
constexpr size_t OUT_OFF_OUT   = 0;                                   // [64,197,768]
constexpr size_t OUT_OFF_INDEX = (size_t)BATCH * NTOK * CDIM;         // [64,137,768]
constexpr size_t OUT_OFF_IDX   = OUT_OFF_INDEX + (size_t)BATCH * LEFT * CDIM; // [64,137]
constexpr size_t OUT_OFF_CLS   = OUT_OFF_IDX + (size_t)BATCH * LEFT;  // [64,196]

// Workspace layout (float units; bf16 regions counted as elems/2)
constexpr size_t WS_CLSPH = 0;                                        // B*H*196
constexpr size_t WS_CLSF  = WS_CLSPH + (size_t)BH * (NTOK - 1);
constexpr size_t WS_IDXI  = WS_CLSF  + (size_t)BATCH * (NTOK - 1);
constexpr size_t WS_Q0    = WS_IDXI  + (size_t)BATCH * LEFT;          // [64,768]
constexpr size_t WS_XB    = WS_Q0  + (size_t)BATCH * CDIM;            // [MPAD,768] bf16
constexpr size_t WS_WB    = WS_XB  + (size_t)MPAD * CDIM / 2;         // [2304,768] bf16
constexpr size_t WS_PB    = WS_WB  + (size_t)3 * CDIM * CDIM / 2;     // [768,768] bf16
constexpr size_t WS_QB    = WS_PB  + (size_t)CDIM * CDIM / 2;         // [BH,197,64] bf16
constexpr size_t WS_KB    = WS_QB  + (size_t)BH * NTOK * HD / 2;      // [BH,197,64] bf16
constexpr size_t WS_VTB   = WS_KB  + (size_t)BH * NTOK * HD / 2;      // [BH,64,224] bf16
constexpr size_t WS_AOB   = WS_VTB + (size_t)BH * HD * KPAD / 2;      // [MPAD,768] bf16
constexpr size_t WS_U     = WS_AOB + (size_t)MPAD * CDIM / 2;         // [BH,768] fp32
constexpr size_t WS_S     = WS_U   + (size_t)BH * CDIM;               // [BH,208] fp32

typedef __attribute__((ext_vector_type(8))) short short8;
typedef __attribute__((ext_vector_type(4))) float floatx4;

__device__ __forceinline__ ushort f2bf(float x) {
    __hip_bfloat16 h = __float2bfloat16(x);
    return *(ushort*)&h;
}

// async global->LDS, 16B per lane; LDS dest must be wave-uniform base + lane*16
__device__ __forceinline__ void load_lds16(const ushort* g, ushort* l) {
    __builtin_amdgcn_global_load_lds(
        (const __attribute__((address_space(1))) uint32_t*)(uintptr_t)g,
        (__attribute__((address_space(3))) uint32_t*)(uint32_t)(uintptr_t)l,
        16, 0, 0);
}

// ---------------------------------------------------------------------------
// fp32 -> bf16 cast, zero padding up to npad4 float4s.
// ---------------------------------------------------------------------------
__global__ __launch_bounds__(256) void cast_kernel(const float* __restrict__ src,
                                                   ushort* __restrict__ dst,
                                                   int n4, int npad4) {
    int i = blockIdx.x * 256 + threadIdx.x;
    if (i >= npad4) return;
    ushort4 h4 = make_ushort4(0, 0, 0, 0);
    if (i < n4) {
        float4 a = ((const float4*)src)[i];
        h4 = make_ushort4(f2bf(a.x), f2bf(a.y), f2bf(a.z), f2bf(a.w));
    }
    ((ushort4*)dst)[i] = h4;
}

// zero the padded key columns of Vt (cols 197..223) — poison would NaN the PV MFMA
__global__ void vt_pad_kernel(ushort* __restrict__ Vtb) {
    int tid = blockIdx.x * 256 + threadIdx.x;
    constexpr int PADW = KPAD - NTOK;               // 27
    if (tid >= BH * HD * PADW) return;
    int row = tid / PADW;
    int col = NTOK + (tid - row * PADW);
    Vtb[(size_t)row * KPAD + col] = 0;
}

// ---------------------------------------------------------------------------
// Exact fp32 q row-0 projection: q0[b, c] = x[b,0,:] . qkv_w[c,:] + qkv_b[c]
// ---------------------------------------------------------------------------
__global__ __launch_bounds__(256) void q0_kernel(const float* __restrict__ x,
                                                 const float* __restrict__ qkv_w,
                                                 const float* __restrict__ qkv_b,
                                                 float* __restrict__ q0) {
    int tid = blockIdx.x * 256 + threadIdx.x;
    if (tid >= BATCH * CDIM) return;
    int b = tid / CDIM, c = tid - b * CDIM;
    const float* xr = x + (size_t)b * NTOK * CDIM;
    const float* wr = qkv_w + (size_t)c * CDIM;
    float s = 0.f;
    for (int k = 0; k < CDIM; k += 4) {
        float4 xv = *(const float4*)(xr + k);
        float4 wv = *(const float4*)(wr + k);
        s += xv.x * wv.x + xv.y * wv.y + xv.z * wv.z + xv.w * wv.w;
    }
    q0[tid] = s + qkv_b[c];
}

// ---------------------------------------------------------------------------
// u[bh, c] = sum_d q0[b, h*64+d] * Wk[h*64+d, c]   (Wk = qkv_w rows 768..1535)
// ---------------------------------------------------------------------------
__global__ __launch_bounds__(256) void u_kernel(const float* __restrict__ q0,
                                                const float* __restrict__ qkv_w,
                                                float* __restrict__ U) {
    const int bh = blockIdx.x;
    const int b  = bh / NH;
    const int h  = bh - b * NH;
    const int t  = threadIdx.x;

    __shared__ float q0s[HD];
    if (t < HD) q0s[t] = q0[(size_t)b * CDIM + h * HD + t];
    __syncthreads();

    const float* wk = qkv_w + (size_t)(CDIM + h * HD) * CDIM;
    float a0 = 0.f, a1 = 0.f, a2 = 0.f;
    for (int d = 0; d < HD; d++) {
        const float qd = q0s[d];
        const float* row = wk + (size_t)d * CDIM;
        a0 = fmaf(qd, row[t],       a0);
        a1 = fmaf(qd, row[t + 256], a1);
        a2 = fmaf(qd, row[t + 512], a2);
    }
    float* ub = U + (size_t)bh * CDIM;
    ub[t] = a0; ub[t + 256] = a1; ub[t + 512] = a2;
}

// ---------------------------------------------------------------------------
// S[bh, j] = u[bh,:] . x[b,j,:]   — 4 waves per block, one (j,b) per wave.
// ---------------------------------------------------------------------------
__global__ __launch_bounds__(256) void score_kernel(const float* __restrict__ x,
                                                    const float* __restrict__ U,
                                                    float* __restrict__ S) {
    const int wv   = threadIdx.x >> 6;
    const int lane = threadIdx.x & 63;
    const int j    = blockIdx.x * 4 + wv;
    const int b    = blockIdx.y;
    if (j >= NTOK) return;

    const float* xr = x + ((size_t)b * NTOK + j) * CDIM;
    float4 xv[3];
#pragma unroll
    for (int i = 0; i < 3; i++) xv[i] = *(const float4*)(xr + lane * 4 + i * 256);

    for (int h = 0; h < NH; h++) {
        const float* ur = U + (size_t)(b * NH + h) * CDIM;
        float s = 0.f;
#pragma unroll
        for (int i = 0; i < 3; i++) {
            float4 uv = *(const float4*)(ur + lane * 4 + i * 256);
            s += xv[i].x * uv.x + xv[i].y * uv.y + xv[i].z * uv.z + xv[i].w * uv.w;
        }
#pragma unroll
        for (int off = 32; off >= 1; off >>= 1) s += __shfl_xor(s, off);
        if (lane == 0) S[(size_t)(b * NH + h) * SPAD + j] = s;
    }
}

// ---------------------------------------------------------------------------
// Softmax of cls row per bh: s_j = (S[j] + q0_h.bk_h) * scale; probs for j>=1.
// ---------------------------------------------------------------------------
__global__ __launch_bounds__(64) void cls_softmax_kernel(const float* __restrict__ S,
                                                         const float* __restrict__ q0,
                                                         const float* __restrict__ qkv_b,
                                                         float* __restrict__ CLSPH) {
    const int bh   = blockIdx.x;
    const int b    = bh / NH;
    const int h    = bh - b * NH;
    const int lane = threadIdx.x;

    float qb = q0[(size_t)b * CDIM + h * HD + lane] * qkv_b[CDIM + h * HD + lane];
#pragma unroll
    for (int off = 32; off >= 1; off >>= 1) qb += __shfl_xor(qb, off);

    const float* Sr = S + (size_t)bh * SPAD;
    float sv[4];
    float mloc = -INFINITY;
#pragma unroll
    for (int i = 0; i < 4; i++) {
        const int j = lane + i * 64;
        sv[i] = (j < NTOK) ? (Sr[j] + qb) * 0.125f : -INFINITY;
        mloc = fmaxf(mloc, sv[i]);
    }
#pragma unroll
    for (int off = 32; off >= 1; off >>= 1) mloc = fmaxf(mloc, __shfl_xor(mloc, off));

    float pv[4], ls = 0.f;
#pragma unroll
    for (int i = 0; i < 4; i++) { pv[i] = expf(sv[i] - mloc); ls += pv[i]; }  // exp(-inf)=0
#pragma unroll
    for (int off = 32; off >= 1; off >>= 1) ls += __shfl_xor(ls, off);

    const float inv = 1.f / ls;
#pragma unroll
    for (int i = 0; i < 4; i++) {
        const int j = lane + i * 64;
        if (j >= 1 && j < NTOK)
            CLSPH[(size_t)bh * (NTOK - 1) + (j - 1)] = pv[i] * inv;
    }
}

// ---------------------------------------------------------------------------
// Plain-bf16 MFMA GEMM: O = A @ W^T + bias.  128x128 tile, BK=32, 4 waves,
// 2-stage double-buffered LDS + XCD-aware block swizzle: flat block id is
// remapped so all NCOLS col-blocks of one row-tile land on the same XCD
// (f&7), making A-tile reuse L2-local (cuts the 4x HBM over-fetch and the
// ~900cyc HBM-miss staging latency the per-iter barrier drain exposes).
// MODE 0: fp32 row-major O0[Mvalid, N].
// MODE 1: qkv scatter (bf16): q -> O0q[bh][tok][64], k -> O1k[bh][tok][64],
//         v -> O2vt[bh][d][KPAD]  (transposed!)
// ---------------------------------------------------------------------------
template <int MODE, int NCOLS>
__global__ __launch_bounds__(256) void mfma_gemm(const ushort* __restrict__ A,
                                                 const ushort* __restrict__ W,
                                                 const float* __restrict__ bias,
                                                 float* __restrict__ O0f,
                                                 ushort* __restrict__ O0q,
                                                 ushort* __restrict__ O1k,
                                                 ushort* __restrict__ O2vt,
                                                 int Mvalid, int N, int K) {
    __shared__ ushort sA[2][128 * 32], sB[2][128 * 32];

    const int t    = threadIdx.x;
    const int lane = t & 63;
    const int w    = t >> 6;
    const int wm   = (w & 1) * 64;
    const int wn   = (w >> 1) * 64;

    // XCD-aware swizzle: row-tile r -> XCD r%8; cols of r stay on that XCD.
    int row, col;
    {
        const int f = blockIdx.x;
        constexpr int RFULL = NROWB & ~7;            // 96
        constexpr int FULL  = RFULL * NCOLS;
        if (f < FULL) {
            const int s = f >> 3;
            col = s % NCOLS;
            row = (s / NCOLS) * 8 + (f & 7);
        } else {
            const int g = f - FULL;
            row = RFULL + g / NCOLS;
            col = g % NCOLS;
        }
    }
    const int rowBase = row * 128;
    const int colBase = col * 128;

    floatx4 acc[4][4];
#pragma unroll
    for (int i = 0; i < 4; i++)
#pragma unroll
        for (int j = 0; j < 4; j++)
#pragma unroll
            for (int r = 0; r < 4; r++) acc[i][j][r] = 0.f;

    const int srow = t >> 2;
    const int skp  = (t & 3) * 8;
    const ushort* gA0 = A + (size_t)(rowBase + srow) * K + skp;
    const ushort* gB0 = W + (size_t)(colBase + srow) * K + skp;
    const size_t rstep = (size_t)64 * K;
    const int fr = lane & 15;
    const int fq = lane >> 4;

    // prologue: stage k0=0 into buffer 0
    load_lds16(gA0,         sA[0] + t * 8);
    load_lds16(gA0 + rstep, sA[0] + t * 8 + 2048);
    load_lds16(gB0,         sB[0] + t * 8);
    load_lds16(gB0 + rstep, sB[0] + t * 8 + 2048);

    int cur = 0;
    for (int k0 = 0; k0 < K; k0 += 32) {
        __syncthreads();   // drains vmcnt -> buf[cur] ready; orders buf[cur^1] reuse
        const int kn = k0 + 32;
        if (kn < K) {      // prefetch next tile into the other buffer
            load_lds16(gA0 + kn,         sA[cur ^ 1] + t * 8);
            load_lds16(gA0 + kn + rstep, sA[cur ^ 1] + t * 8 + 2048);
            load_lds16(gB0 + kn,         sB[cur ^ 1] + t * 8);
            load_lds16(gB0 + kn + rstep, sB[cur ^ 1] + t * 8 + 2048);
        }

        short8 af[4], bf[4];
#pragma unroll
        for (int i = 0; i < 4; i++) {
            af[i] = *(const short8*)&sA[cur][(wm + i * 16 + fr) * 32 + fq * 8];
            bf[i] = *(const short8*)&sB[cur][(wn + i * 16 + fr) * 32 + fq * 8];
        }
#pragma unroll
        for (int i = 0; i < 4; i++)
#pragma unroll
            for (int j = 0; j < 4; j++)
                acc[i][j] = __builtin_amdgcn_mfma_f32_16x16x32_bf16(af[i], bf[j], acc[i][j], 0, 0, 0);
        cur ^= 1;
    }

    // epilogue: C/D layout col(n)=lane&15, row(m)=(lane>>4)*4+reg
#pragma unroll
    for (int j = 0; j < 4; j++) {
        const int n  = colBase + wn + j * 16 + fr;
        const float bq = bias[n];
        if (MODE == 0) {
#pragma unroll
            for (int i = 0; i < 4; i++) {
                const int mb = rowBase + wm + i * 16 + fq * 4;
#pragma unroll
                for (int r = 0; r < 4; r++) {
                    const int m = mb + r;
                    if (m < Mvalid) O0f[(size_t)m * N + n] = acc[i][j][r] + bq;
                }
            }
        } else {
            const int which = n / CDIM;
            const int nc    = n - which * CDIM;
            const int h     = nc >> 6;
            const int d     = nc & 63;
#pragma unroll
            for (int i = 0; i < 4; i++) {
                const int mb = rowBase + wm + i * 16 + fq * 4;
#pragma unroll
                for (int r = 0; r < 4; r++) {
                    const int m = mb + r;
                    if (m < Mvalid) {
                        const int b   = m / NTOK;
                        const int tok = m - b * NTOK;
                        const int bh  = b * NH + h;
                        const ushort val = f2bf(acc[i][j][r] + bq);
                        if (which == 0)      O0q[((size_t)bh * NTOK + tok) * HD + d] = val;
                        else if (which == 1) O1k[((size_t)bh * NTOK + tok) * HD + d] = val;
                        else                 O2vt[((size_t)bh * HD + d) * KPAD + tok] = val;
                    }
                }
            }
        }
    }
}

// ---------------------------------------------------------------------------
// MFMA flash attention: one wave (64 threads) per (q-tile, b*h).
// S^T = K.Q^T so queries sit in C-columns; online softmax per-lane + two
// shfl_xor quad-reduces. P via 1KB LDS roundtrip; PV uses transposed-V frags.
// ---------------------------------------------------------------------------
__global__ __launch_bounds__(64) void attn_mfma_kernel(const ushort* __restrict__ Qb,
                                                       const ushort* __restrict__ Kb,
                                                       const ushort* __restrict__ Vtb,
                                                       ushort* __restrict__ AOb) {
    const int qt = blockIdx.x;          // 0..12
    const int bh = blockIdx.y;          // 0..767
    const int b  = bh / NH;
    const int h  = bh - b * NH;
    const int lane = threadIdx.x;
    const int qc   = lane & 15;
    const int quad = lane >> 4;

    __shared__ ushort Pl[16][32];
    __shared__ float  alf[16], lf[16];

    const ushort* Qh = Qb  + (size_t)bh * NTOK * HD;
    const ushort* Kh = Kb  + (size_t)bh * NTOK * HD;
    const ushort* Vh = Vtb + (size_t)bh * HD * KPAD;

    const int qrow = min(qt * 16 + qc, NTOK - 1);
    const short8 qf0 = *(const short8*)(Qh + (size_t)qrow * HD + quad * 8);
    const short8 qf1 = *(const short8*)(Qh + (size_t)qrow * HD + 32 + quad * 8);

    floatx4 o[4];
#pragma unroll
    for (int s = 0; s < 4; s++)
#pragma unroll
        for (int r = 0; r < 4; r++) o[s][r] = 0.f;
    float m = -INFINITY, l = 0.f;

    for (int c0 = 0; c0 < NTOK; c0 += 32) {
        const int kr0 = min(c0 + qc, NTOK - 1);
        const int kr1 = min(c0 + 16 + qc, NTOK - 1);
        short8 kf00 = *(const short8*)(Kh + (size_t)kr0 * HD + quad * 8);
        short8 kf01 = *(const short8*)(Kh + (size_t)kr0 * HD + 32 + quad * 8);
        short8 kf10 = *(const short8*)(Kh + (size_t)kr1 * HD + quad * 8);
        short8 kf11 = *(const short8*)(Kh + (size_t)kr1 * HD + 32 + quad * 8);

        floatx4 s0 = {0.f, 0.f, 0.f, 0.f}, s1 = {0.f, 0.f, 0.f, 0.f};
        s0 = __builtin_amdgcn_mfma_f32_16x16x32_bf16(kf00, qf0, s0, 0, 0, 0);
        s0 = __builtin_amdgcn_mfma_f32_16x16x32_bf16(kf01, qf1, s0, 0, 0, 0);
        s1 = __builtin_amdgcn_mfma_f32_16x16x32_bf16(kf10, qf0, s1, 0, 0, 0);
        s1 = __builtin_amdgcn_mfma_f32_16x16x32_bf16(kf11, qf1, s1, 0, 0, 0);

        float sv[8];
        float mloc = -INFINITY;
#pragma unroll
        for (int r = 0; r < 4; r++) {
            const int key0 = c0 + quad * 4 + r;
            const int key1 = key0 + 16;
            sv[r]     = (key0 < NTOK) ? s0[r] * 0.125f : -1e30f;
            sv[4 + r] = (key1 < NTOK) ? s1[r] * 0.125f : -1e30f;
            mloc = fmaxf(mloc, fmaxf(sv[r], sv[4 + r]));
        }
        mloc = fmaxf(mloc, __shfl_xor(mloc, 16));
        mloc = fmaxf(mloc, __shfl_xor(mloc, 32));
        const float mnew  = fmaxf(m, mloc);
        const float alpha = __expf(m - mnew);
        float p[8], ps = 0.f;
#pragma unroll
        for (int i = 0; i < 8; i++) { p[i] = __expf(sv[i] - mnew); ps += p[i]; }
        ps += __shfl_xor(ps, 16);
        ps += __shfl_xor(ps, 32);
        l = l * alpha + ps;
        m = mnew;

#pragma unroll
        for (int r = 0; r < 4; r++) {
            Pl[qc][quad * 4 + r]      = f2bf(p[r]);
            Pl[qc][16 + quad * 4 + r] = f2bf(p[4 + r]);
        }
        if (quad == 0) alf[qc] = alpha;
        __syncthreads();

        float ar[4];
#pragma unroll
        for (int r = 0; r < 4; r++) ar[r] = alf[quad * 4 + r];
#pragma unroll
        for (int s = 0; s < 4; s++)
#pragma unroll
            for (int r = 0; r < 4; r++) o[s][r] *= ar[r];

        const short8 pf = *(const short8*)&Pl[qc][quad * 8];
#pragma unroll
        for (int s = 0; s < 4; s++) {
            const short8 vf = *(const short8*)(Vh + (size_t)(s * 16 + qc) * KPAD + c0 + quad * 8);
            o[s] = __builtin_amdgcn_mfma_f32_16x16x32_bf16(pf, vf, o[s], 0, 0, 0);
        }
        __syncthreads();
    }

    if (quad == 0) lf[qc] = l;
    __syncthreads();

#pragma unroll
    for (int r = 0; r < 4; r++) {
        const int tok = qt * 16 + quad * 4 + r;
        if (tok >= NTOK) continue;
        const float inv = 1.f / lf[quad * 4 + r];
        ushort* dst = AOb + ((size_t)(b * NTOK + tok)) * CDIM + h * HD;
#pragma unroll
        for (int s = 0; s < 4; s++) dst[s * 16 + qc] = f2bf(o[s][r] * inv);
    }
}

// ---------------------------------------------------------------------------
__global__ void cls_mean_kernel(const float* __restrict__ CLSPH,
                                float* __restrict__ clsF,
                                float* __restrict__ outCls) {
    int tid = blockIdx.x * 256 + threadIdx.x;
    if (tid >= BATCH * (NTOK - 1)) return;
    int b = tid / (NTOK - 1);
    int j = tid - b * (NTOK - 1);
    float s = 0.f;
#pragma unroll
    for (int h = 0; h < NH; h++) s += CLSPH[(size_t)(b * NH + h) * (NTOK - 1) + j];
    float v = s * (1.f / 12.f);
    clsF[tid]   = v;
    outCls[tid] = v;
}

__global__ void topk_kernel(const float* __restrict__ clsF,
                            int* __restrict__ idxI,
                            float* __restrict__ idxOut) {
    const int b = blockIdx.x;
    const int t = threadIdx.x;
    __shared__ float v[NTOK - 1];
    if (t < NTOK - 1) v[t] = clsF[b * (NTOK - 1) + t];
    __syncthreads();
    if (t < NTOK - 1) {
        float vi = v[t];
        int rank = 0;
        for (int j = 0; j < NTOK - 1; j++) {
            float vj = v[j];
            rank += (vj > vi) || (vj == vi && j < t);
        }
        if (rank < LEFT) {
            idxI[b * LEFT + rank]   = t;
            idxOut[b * LEFT + rank] = (float)t;
        }
    }
}

// index = broadcast idx over channel dim, float4-vectorized (CDIM%4==0)
__global__ void fill_index_kernel(const int* __restrict__ idxI,
                                  float* __restrict__ dst) {
    int tid = blockIdx.x * 256 + threadIdx.x;
    constexpr int C4 = CDIM / 4;
    if (tid >= BATCH * LEFT * C4) return;
    float v = (float)idxI[tid / C4];
    ((float4*)dst)[tid] = make_float4(v, v, v, v);
}

extern "C" void kernel_launch(void* const* d_in, const int* in_sizes, int n_in,
                              void* d_out, int out_size, void* d_ws, size_t ws_size,
                              hipStream_t stream) {
    const float* x      = (const float*)d_in[0];
    const float* qkv_w  = (const float*)d_in[1];  // [2304,768]
    const float* qkv_b  = (const float*)d_in[2];  // [2304]
    const float* proj_w = (const float*)d_in[3];  // [768,768]
    const float* proj_b = (const float*)d_in[4];  // [768]
    float* out = (float*)d_out;

    float*  ws    = (float*)d_ws;
    float*  clsph = ws + WS_CLSPH;
    float*  clsf  = ws + WS_CLSF;
    int*    idxi  = (int*)(ws + WS_IDXI);
    float*  q0    = ws + WS_Q0;
    ushort* xb    = (ushort*)(ws + WS_XB);
    ushort* wb    = (ushort*)(ws + WS_WB);
    ushort* pb    = (ushort*)(ws + WS_PB);
    ushort* qb    = (ushort*)(ws + WS_QB);
    ushort* kb    = (ushort*)(ws + WS_KB);
    ushort* vtb   = (ushort*)(ws + WS_VTB);
    ushort* aob   = (ushort*)(ws + WS_AOB);
    float*  U     = ws + WS_U;
    float*  S     = ws + WS_S;

    // 1) fp32 -> bf16 casts (+row padding for MPAD), Vt pad-column zeroing
    {
        int n4 = MROWS * CDIM / 4, np4 = MPAD * CDIM / 4;
        cast_kernel<<<(np4 + 255) / 256, 256, 0, stream>>>(x, xb, n4, np4);
        int w4 = 3 * CDIM * CDIM / 4;
        cast_kernel<<<(w4 + 255) / 256, 256, 0, stream>>>(qkv_w, wb, w4, w4);
        int p4 = CDIM * CDIM / 4;
        cast_kernel<<<(p4 + 255) / 256, 256, 0, stream>>>(proj_w, pb, p4, p4);
        int vp = BH * HD * (KPAD - NTOK);
        vt_pad_kernel<<<(vp + 255) / 256, 256, 0, stream>>>(vtb);
    }

    // 2) Exact fp32 cls-score side path (top-k precision domain)
    q0_kernel<<<(BATCH * CDIM + 255) / 256, 256, 0, stream>>>(x, qkv_w, qkv_b, q0);
    u_kernel<<<BH, 256, 0, stream>>>(q0, qkv_w, U);
    score_kernel<<<dim3((NTOK + 3) / 4, BATCH), 256, 0, stream>>>(x, U, S);
    cls_softmax_kernel<<<BH, 64, 0, stream>>>(S, q0, qkv_b, clsph);

    // 3) QKV projection (bf16 MFMA) + scatter q/k bf16, v transposed bf16
    mfma_gemm<1, 18><<<18 * NROWB, 256, 0, stream>>>(
        xb, wb, qkv_b, nullptr, qb, kb, vtb, MROWS, 3 * CDIM, CDIM);

    // 4) MFMA flash attention -> bf16 pre-proj out
    attn_mfma_kernel<<<dim3(13, BH), 64, 0, stream>>>(qb, kb, vtb, aob);

    // 5) Output projection (bf16 MFMA) -> fp32 out
    mfma_gemm<0, 6><<<6 * NROWB, 256, 0, stream>>>(
        aob, pb, proj_b, out + OUT_OFF_OUT, nullptr, nullptr, nullptr,
        MROWS, CDIM, CDIM);

    // 6) Head-average cls attention (exact path)
    cls_mean_kernel<<<(BATCH * (NTOK - 1) + 255) / 256, 256, 0, stream>>>(
        clsph, clsf, out + OUT_OFF_CLS);

    // 7) Exact top-137 (stable descending)
    topk_kernel<<<BATCH, 256, 0, stream>>>(clsf, idxi, out + OUT_OFF_IDX);

    // 8) Broadcast indices over channels (float4)
    fill_index_kernel<<<((size_t)BATCH * LEFT * (CDIM / 4) + 255) / 256, 256, 0, stream>>>(
        idxi, out + OUT_OFF_INDEX);
}